// Round 6
// baseline (1192.201 us; speedup 1.0000x reference)
//
#include <hip/hip_runtime.h>

// RecNet: 100-step recurrent LIF SNN + LI readout. Exact fp64 trajectory.
//   probe   : discovers v_mfma_f64_16x16x4 operand/result lane layouts at runtime
//             (16 hypotheses, validated vs VALU reference, 2 asymmetric value sets).
//   gemm_in : cin = x @ w_in^T, fp64. MFMA path (layout from probe) or VALU fallback.
//             Grid is n-major so blocks sharing an A-panel co-reside (L3 reuse).
//   lif     : persistent, one block per batch element, spike-sparse gather.

#define TT    100
#define BATCH 512
#define FDIM  784
#define HDIM  512
#define ODIM  10
#define NSTATE (BATCH * HDIM)

// DT*TAU_MEM_INV / DT*TAU_SYN_INV round in fp64 exactly to 0.1 / 0.2
#define DTM 0.1
#define DTS 0.2

typedef double f64x4 __attribute__((ext_vector_type(4)));

// Shared layout-hypothesis decoder: H bit0 = A input map, bit1 = B input map,
// bits[3:2] = D map variant. Used by BOTH probe and gemm -> consistent by construction.
__device__ __forceinline__ void h_maps(int H, int lane,
                                       int& am, int& ak, int& bn, int& bk,
                                       int dr[4], int dc[4]) {
  const int l15 = lane & 15, l4 = lane >> 4;
  const int lq = lane >> 2, l3 = lane & 3;
  if (H & 1) { am = lq;  ak = l3; } else { am = l15; ak = l4; }
  if (H & 2) { bn = lq;  bk = l3; } else { bn = l15; bk = l4; }
  const int dmode = H >> 2;
#pragma unroll
  for (int r = 0; r < 4; ++r) {
    const int rr = (dmode & 1) ? (l4 + (r << 2)) : ((l4 << 2) + r);
    if (dmode & 2) { dr[r] = l15; dc[r] = rr; }
    else           { dr[r] = rr;  dc[r] = l15; }
  }
}

// ---------------- probe: find the true f64 MFMA layout ----------------
__global__ __launch_bounds__(64) void probe_kernel(int* __restrict__ flag) {
  const int lane = threadIdx.x;
  int winner = -1;
  for (int H = 0; H < 16; ++H) {
    int am, ak, bn, bk, dr[4], dc[4];
    h_maps(H, lane, am, ak, bn, bk, dr, dc);
    bool ok = true;
#pragma unroll
    for (int s = 0; s < 2; ++s) {
      const int c0 = s ? 2 : 3, c1 = s ? 13 : 7, c2 = s ? 9 : 5, c3 = s ? 4 : 11;
      const double a = (double)(1 + c0 * am + c1 * ak);   // claims A[m][k] = 1+c0*m+c1*k
      const double b = (double)(1 + c2 * bn + c3 * bk);   // claims B[k][n] = 1+c2*n+c3*k
      f64x4 d = {0.0, 0.0, 0.0, 0.0};
      d = __builtin_amdgcn_mfma_f64_16x16x4f64(a, b, d, 0, 0, 0);
#pragma unroll
      for (int r = 0; r < 4; ++r) {
        double ref = 0.0;
#pragma unroll
        for (int k = 0; k < 4; ++k)
          ref += (double)((1 + c0 * dr[r] + c1 * k) * (1 + c2 * dc[r] + c3 * k));
        ok = ok && (d[r] == ref);   // exact small-integer math: == is valid
      }
    }
    if (__all(ok) && winner < 0) winner = H;
  }
  if (lane == 0) *flag = winner;
}

// ---------------- K1: C[m][n] = sum_k A[m][k]*B[n][k], fp64 ----------------
// M=51200 K=784 N=512. Block 64x64, BK=16 (784=49*16), 256 thr = 4 waves.
// Grid dim3(8, 800): x = n-block (8), y = m-block -> A-panel reuse across x.
__global__ __launch_bounds__(256) void gemm_in_kernel(const float* __restrict__ A,
                                                      const float* __restrict__ B,
                                                      double* __restrict__ C,
                                                      const int* __restrict__ flag) {
  __shared__ __align__(16) double Al[4][16][16];   // [mtile][k][m16]
  __shared__ __align__(16) double Bl[4][16][16];   // [ntile][k][n16]
  const int tid  = threadIdx.x;
  const int lane = tid & 63;
  const int qm   = (tid >> 6) & 1;
  const int qn   = tid >> 7;
  const int n0 = blockIdx.x << 6;
  const int m0 = blockIdx.y << 6;
  const int srow = tid >> 2;         // 0..63
  const int skc  = (tid & 3) << 2;   // 0,4,8,12
  const int st = srow >> 4, sr = srow & 15;
  const int H = flag[0];

  const float* Arow = A + (size_t)(m0 + srow) * FDIM + skc;
  const float* Brow = B + (size_t)(n0 + srow) * FDIM + skc;

  if (H >= 0) {
    // ---------- MFMA path ----------
    int am, ak, bn, bk, dr[4], dc[4];
    h_maps(H, lane, am, ak, bn, bk, dr, dc);
    f64x4 acc[2][2] = {};
    for (int kt = 0; kt < 49; ++kt) {
      __syncthreads();
      const float4 a4 = *(const float4*)(Arow + kt * 16);
      Al[st][skc + 0][sr] = (double)a4.x;
      Al[st][skc + 1][sr] = (double)a4.y;
      Al[st][skc + 2][sr] = (double)a4.z;
      Al[st][skc + 3][sr] = (double)a4.w;
      const float4 b4 = *(const float4*)(Brow + kt * 16);
      Bl[st][skc + 0][sr] = (double)b4.x;
      Bl[st][skc + 1][sr] = (double)b4.y;
      Bl[st][skc + 2][sr] = (double)b4.z;
      Bl[st][skc + 3][sr] = (double)b4.w;
      __syncthreads();
#pragma unroll
      for (int ks = 0; ks < 4; ++ks) {
        const double a0 = Al[(qm << 1) + 0][(ks << 2) + ak][am];
        const double a1 = Al[(qm << 1) + 1][(ks << 2) + ak][am];
        const double b0 = Bl[(qn << 1) + 0][(ks << 2) + bk][bn];
        const double b1 = Bl[(qn << 1) + 1][(ks << 2) + bk][bn];
        acc[0][0] = __builtin_amdgcn_mfma_f64_16x16x4f64(a0, b0, acc[0][0], 0, 0, 0);
        acc[0][1] = __builtin_amdgcn_mfma_f64_16x16x4f64(a0, b1, acc[0][1], 0, 0, 0);
        acc[1][0] = __builtin_amdgcn_mfma_f64_16x16x4f64(a1, b0, acc[1][0], 0, 0, 0);
        acc[1][1] = __builtin_amdgcn_mfma_f64_16x16x4f64(a1, b1, acc[1][1], 0, 0, 0);
      }
    }
#pragma unroll
    for (int i = 0; i < 2; ++i)
#pragma unroll
      for (int j = 0; j < 2; ++j)
#pragma unroll
        for (int r = 0; r < 4; ++r)
          C[(size_t)(m0 + (((qm << 1) + i) << 4) + dr[r]) * HDIM
            + n0 + (((qn << 1) + j) << 4) + dc[r]] = acc[i][j][r];
  } else {
    // ---------- VALU fallback (round-3 verified structure, 64x64, 4x4 fp64) ----------
    float* Asf = (float*)&Al[0][0][0];   // [16][68] floats (4352 B, fits in Al)
    float* Bsf = (float*)&Bl[0][0][0];
    const int tn = tid & 15, tm = tid >> 4;
    const int lrow = tid >> 2, lkc = (tid & 3) << 2;
    double acc[4][4] = {};
    for (int kt = 0; kt < 49; ++kt) {
      __syncthreads();
      const float4 a = *(const float4*)(A + (size_t)(m0 + lrow) * FDIM + kt * 16 + lkc);
      Asf[(lkc + 0) * 68 + lrow] = a.x; Asf[(lkc + 1) * 68 + lrow] = a.y;
      Asf[(lkc + 2) * 68 + lrow] = a.z; Asf[(lkc + 3) * 68 + lrow] = a.w;
      const float4 b = *(const float4*)(B + (size_t)(n0 + lrow) * FDIM + kt * 16 + lkc);
      Bsf[(lkc + 0) * 68 + lrow] = b.x; Bsf[(lkc + 1) * 68 + lrow] = b.y;
      Bsf[(lkc + 2) * 68 + lrow] = b.z; Bsf[(lkc + 3) * 68 + lrow] = b.w;
      __syncthreads();
#pragma unroll
      for (int kk = 0; kk < 16; ++kk) {
        const float4 af = *(const float4*)&Asf[kk * 68 + (tm << 2)];
        const float4 bf = *(const float4*)&Bsf[kk * 68 + (tn << 2)];
        const double amv[4] = {(double)af.x, (double)af.y, (double)af.z, (double)af.w};
        const double bnv[4] = {(double)bf.x, (double)bf.y, (double)bf.z, (double)bf.w};
#pragma unroll
        for (int i = 0; i < 4; ++i)
#pragma unroll
          for (int j = 0; j < 4; ++j) acc[i][j] += amv[i] * bnv[j];
      }
    }
#pragma unroll
    for (int i = 0; i < 4; ++i) {
      double* crow = C + (size_t)(m0 + (tm << 2) + i) * HDIM + n0 + (tn << 2);
      *(double2*)(crow)     = make_double2(acc[i][0], acc[i][1]);
      *(double2*)(crow + 2) = make_double2(acc[i][2], acc[i][3]);
    }
  }
}

// ---------------- transpose w_rec [512][512] -> wrt [k][h] ----------------
__global__ __launch_bounds__(256) void transpose_kernel(const float* __restrict__ src,
                                                        float* __restrict__ dst) {
  __shared__ float tile[32][33];
  const int bx = blockIdx.x & 15, by = blockIdx.x >> 4;
  const int tx = threadIdx.x & 31, ty = threadIdx.x >> 5;
  const int x = (bx << 5) + tx;
#pragma unroll
  for (int s = 0; s < 32; s += 8)
    tile[ty + s][tx] = src[(size_t)((by << 5) + ty + s) * HDIM + x];
  __syncthreads();
  const int xo = (by << 5) + tx;
#pragma unroll
  for (int s = 0; s < 32; s += 8)
    dst[(size_t)((bx << 5) + ty + s) * HDIM + xo] = tile[tx][ty + s];
}

// ---------------- w_out [10][512] -> wot [k][16] (cols 10..15 stay zero) -------
__global__ __launch_bounds__(256) void wot_kernel(const float* __restrict__ w_out,
                                                  float* __restrict__ wot) {
  const int k = (blockIdx.x << 8) + threadIdx.x;  // 0..511
#pragma unroll
  for (int o = 0; o < ODIM; ++o) wot[(k << 4) + o] = w_out[(size_t)o * HDIM + k];
}

// ---------------- K2: persistent LIF+LI, one block per batch element ----------
__global__ __launch_bounds__(256) void lif_kernel(const double* __restrict__ cin,
                                                  const float* __restrict__ wrt,
                                                  const float* __restrict__ wot,
                                                  float* __restrict__ out) {
  const int b = blockIdx.x;
  const int tid = threadIdx.x;
  const int h0 = tid, h1 = tid + 256;

  __shared__ unsigned long long masks[8];
  __shared__ int offs[9];                       // offs[8] = nfire (persists 1 step)
  __shared__ __align__(8) unsigned short list[528];
  __shared__ double ypart[256];

  if (tid == 0) offs[8] = 0;                    // empty list at t=0
  __syncthreads();

  double v0 = 0.0, v1 = 0.0, i0 = 0.0, i1 = 0.0;
  double lv = 0.0, li = 0.0;                    // live in threads 0..9

  const double* cinb = cin + (size_t)b * HDIM;
  float* outb = out + (size_t)b * ODIM;

  for (int t = 0; t < TT; ++t) {
    // (a) LIF: spikes from old state, then decay
    const double vd0 = v0 + DTM * ((0.0 - v0) + i0);
    const double vd1 = v1 + DTM * ((0.0 - v1) + i1);
    const bool s0 = (vd0 - 1.0) > 0.0;
    const bool s1 = (vd1 - 1.0) > 0.0;
    v0 = s0 ? 0.0 : vd0;
    v1 = s1 ? 0.0 : vd1;
    i0 = i0 - DTS * i0;
    i1 = i1 - DTS * i1;

    // issue cin loads early (consumed after gather)
    const double c0 = cinb[(size_t)t * NSTATE + h0];
    const double c1 = cinb[(size_t)t * NSTATE + h1];

    // (b) rec gather over PREVIOUS step's fired list (z(t-1) @ W_rec^T)
    {
      const int nf = offs[8];
      const int nfp = (nf + 3) & ~3;            // list padded with k=512 (zero row)
      if (nfp > 0) {
        float A0[4], A1[4], B0[4] = {}, B1[4] = {};
#define LOADG(base, X0, X1)                                                   \
        do {                                                                  \
          const unsigned long long le = *(const unsigned long long*)&list[base]; \
          const int k0 = (int)(le & 0xffffu), k1 = (int)((le >> 16) & 0xffffu); \
          const int k2 = (int)((le >> 32) & 0xffffu), k3 = (int)(le >> 48);   \
          X0[0] = wrt[(k0 << 9) + h0]; X1[0] = wrt[(k0 << 9) + h1];           \
          X0[1] = wrt[(k1 << 9) + h0]; X1[1] = wrt[(k1 << 9) + h1];           \
          X0[2] = wrt[(k2 << 9) + h0]; X1[2] = wrt[(k2 << 9) + h1];           \
          X0[3] = wrt[(k3 << 9) + h0]; X1[3] = wrt[(k3 << 9) + h1];           \
        } while (0)
        LOADG(0, A0, A1);
        for (int g = 0; g < nfp; g += 4) {
          if (g + 4 < nfp) LOADG(g + 4, B0, B1);
          i0 += (double)A0[0]; i1 += (double)A1[0];
          i0 += (double)A0[1]; i1 += (double)A1[1];
          i0 += (double)A0[2]; i1 += (double)A1[2];
          i0 += (double)A0[3]; i1 += (double)A1[3];
#pragma unroll
          for (int j = 0; j < 4; ++j) { A0[j] = B0[j]; A1[j] = B1[j]; }
        }
#undef LOADG
      }
    }
    i0 += c0;
    i1 += c1;

    __syncthreads();  // B1: gathers done reading list/offs before overwrite

    // (c) ballot + compact current spikes
    {
      const unsigned long long m0 = __ballot(s0);
      const unsigned long long m1 = __ballot(s1);
      const int w = tid >> 6;
      if ((tid & 63) == 0) { masks[w] = m0; masks[4 + w] = m1; }
    }
    __syncthreads();  // B2
    if (tid == 0) {
      int r = 0;
#pragma unroll
      for (int q = 0; q < 8; ++q) { offs[q] = r; r += __popcll(masks[q]); }
      offs[8] = r;
    }
    __syncthreads();  // B3
    if (tid < 8) {
      unsigned long long m = masks[tid];
      int o = offs[tid];
      const int base = tid << 6;
      while (m) {
        list[o++] = (unsigned short)(base + __builtin_ctzll(m));
        m &= m - 1;
      }
    }
    if (tid < 4) list[offs[8] + tid] = 512;     // pad for group-of-4 reads
    __syncthreads();  // B4

    // (d) readout y(t) = sum over current fired k of wot[k][o]
    {
      const int o = tid & 15, q = tid >> 4;     // 16 chunks x 16 "outputs" (10 real)
      const int nfc = offs[8];
      double yp = 0.0;
      int kk = q;
      if (kk < nfc) {
        float f = wot[((int)list[kk] << 4) + o];
        for (kk += 16; kk < nfc; kk += 16) {
          const float fn = wot[((int)list[kk] << 4) + o];
          yp += (double)f;
          f = fn;
        }
        yp += (double)f;
      }
      ypart[(o << 4) + q] = yp;
    }
    __syncthreads();  // B5
    if (tid < ODIM) {
      double y = 0.0;
      const double* yr = &ypart[tid << 4];
#pragma unroll
      for (int q = 0; q < 16; ++q) y += yr[q];
      const double lvn = lv + DTM * ((0.0 - lv) + li);   // uses OLD li
      li = (li - DTS * li) + y;
      lv = lvn;
      outb[(size_t)t * (BATCH * ODIM) + tid] = (float)lvn;
    }
  }
}

extern "C" void kernel_launch(void* const* d_in, const int* in_sizes, int n_in,
                              void* d_out, int out_size, void* d_ws, size_t ws_size,
                              hipStream_t stream) {
  const float* x     = (const float*)d_in[0];   // [100,512,784]
  const float* w_in  = (const float*)d_in[1];   // [512,784]
  const float* w_rec = (const float*)d_in[2];   // [512,512]
  const float* w_out = (const float*)d_in[3];   // [10,512]
  float* out = (float*)d_out;                   // [100,512,10] fp32

  const size_t CIN = (size_t)TT * BATCH * HDIM;       // 26,214,400 doubles
  double* cin = (double*)d_ws;
  float* wrt = (float*)(cin + CIN);                   // [513][512], row 512 = zeros
  float* wot = wrt + 513 * 512;                       // [513][16],  row 512 + cols 10..15 zero
  int* flag  = (int*)(wot + 513 * 16);

  const size_t aux_floats = 513ull * 512 + 513ull * 16;
  const size_t need_bytes = CIN * sizeof(double) + aux_floats * sizeof(float) + 16;
  if (ws_size < need_bytes) {
    hipMemsetAsync(d_out, 0x7F, (size_t)out_size * sizeof(float), stream);
    return;
  }

  hipMemsetAsync(wrt, 0, aux_floats * sizeof(float), stream);
  probe_kernel<<<1, 64, 0, stream>>>(flag);
  transpose_kernel<<<256, 256, 0, stream>>>(w_rec, wrt);
  wot_kernel<<<2, 256, 0, stream>>>(w_out, wot);
  gemm_in_kernel<<<dim3(8, 800), 256, 0, stream>>>(x, w_in, cin, flag);
  lif_kernel<<<BATCH, 256, 0, stream>>>(cin, wrt, wot, out);
}